// Round 18
// baseline (15041.080 us; speedup 1.0000x reference)
//
#include <hip/hip_runtime.h>
#include <hip/hip_bf16.h>

#define BB 32
#define SS 128
#define CC 128
#define HH 128
#define OO 64

typedef _Float16 f16;
typedef f16 h2 __attribute__((ext_vector_type(2)));
typedef unsigned u32x4 __attribute__((ext_vector_type(4)));   // 4 packed f16x2 pairs

// Native single-instruction transcendentals (R17-proven: +13%).
__device__ __forceinline__ float exp2n(float x) {
    float r; asm("v_exp_f32 %0, %1" : "=v"(r) : "v"(x)); return r;
}
__device__ __forceinline__ float rcpn(float x) {
    float r; asm("v_rcp_f32 %0, %1" : "=v"(r) : "v"(x)); return r;
}

__device__ __forceinline__ h2 as_h2(unsigned u) { return __builtin_bit_cast(h2, u); }

__device__ __forceinline__ unsigned pack2f(float a, float b) {
    h2 v; v[0] = (f16)a; v[1] = (f16)b;
    return __builtin_bit_cast(unsigned, v);
}
__device__ __forceinline__ u32x4 packrow8(const float* p) {
    u32x4 r;
    r.x = pack2f(p[0], p[1]);
    r.y = pack2f(p[2], p[3]);
    r.z = pack2f(p[4], p[5]);
    r.w = pack2f(p[6], p[7]);
    return r;
}

// 8-elem f16 dot, f32 accumulate; all operands pre-packed f16x2 pairs.
__device__ __forceinline__ float dot4x2(u32x4 w, u32x4 h, float acc) {
    acc = __builtin_amdgcn_fdot2(as_h2(w.x), as_h2(h.x), acc, false);
    acc = __builtin_amdgcn_fdot2(as_h2(w.y), as_h2(h.y), acc, false);
    acc = __builtin_amdgcn_fdot2(as_h2(w.z), as_h2(h.z), acc, false);
    acc = __builtin_amdgcn_fdot2(as_h2(w.w), as_h2(h.w), acc, false);
    return acc;
}

// ROUND-18: 2-WAVE convoy test. R17 (4 waves, 912 cyc/step) has ~300 cyc of
// unattributed barrier/convoy cost. This block = 128 threads = 2 waves;
// thread = j (one per hidden unit), FULL 128-wide dot for rows j / j+128 /
// j+256: 48 pinned u32x4 = 192 weight VGPRs. No dpp reduce, no pair
// redundancy; h-reads are wave-uniform b128 broadcasts (0 conflicts); every
// thread writes its own h[j]. Residency: LDS >80KB -> 1 block/CU -> 2
// waves/CU -> occupancy target 1 wave/SIMD -> 512-VGPR budget, so the ~280
// live set fits (grants have followed demand whenever budget allowed:
// R12/R14/R16/R17). Native trans in log2 domain (R17). 1 barrier/step.
__global__
__attribute__((amdgpu_flat_work_group_size(128, 128), amdgpu_waves_per_eu(1, 2)))
void gru_chain_kernel(
    const float* __restrict__ x,       // (B,S,C)
    const float* __restrict__ h_prev,  // (2,B,H)
    const float* __restrict__ Wih_f, const float* __restrict__ Whh_f,
    const float* __restrict__ bih_f, const float* __restrict__ bhh_f,
    const float* __restrict__ Wih_b, const float* __restrict__ Whh_b,
    const float* __restrict__ bih_b, const float* __restrict__ bhh_b,
    float* __restrict__ hsnap)         // (2, C, B, H) column-end snapshots
{
    const int wg = blockIdx.x;
    const int d  = wg >> 5;        // 0 = forward, 1 = backward
    const int b  = wg & 31;
    const int t  = threadIdx.x;    // 0..127
    const int j  = t;              // hidden index 0..127

    const float* __restrict__ Wih = d ? Wih_b : Wih_f;
    const float* __restrict__ Whh = d ? Whh_b : Whh_f;
    const float* __restrict__ bih = d ? bih_b : bih_f;
    const float* __restrict__ bhh = d ? bhh_b : bhh_f;

    // xs padded: total LDS > 80KB -> 1 block/CU -> 512-VGPR budget.
    __shared__ float xs[SS * CC + 4608];
    __shared__ __align__(16) f16 hbuf[2][136];   // h[j] at f16-offset j, +8 pad

    // stage x[b] (16384 contiguous floats) into LDS, coalesced float4
    {
        const float4* xb4 = reinterpret_cast<const float4*>(x + (size_t)b * SS * CC);
        float4* xs4 = reinterpret_cast<float4*>(xs);
        #pragma unroll
        for (int i = 0; i < 32; ++i) xs4[t + i * 128] = xb4[t + i * 128];
    }

    // 48 NAMED u32x4 (192 VGPRs) of packed f16 pairs: rows j, j+128, j+256,
    // FULL 128 elements each.
    const float* rowr = Whh + (j          ) * HH;
    const float* rowz = Whh + (j +     HH ) * HH;
    const float* rown = Whh + (j + 2 * HH ) * HH;
    u32x4 wr0 = packrow8(rowr +   0), wr1 = packrow8(rowr +   8),
          wr2 = packrow8(rowr +  16), wr3 = packrow8(rowr +  24),
          wr4 = packrow8(rowr +  32), wr5 = packrow8(rowr +  40),
          wr6 = packrow8(rowr +  48), wr7 = packrow8(rowr +  56),
          wr8 = packrow8(rowr +  64), wr9 = packrow8(rowr +  72),
          wrA = packrow8(rowr +  80), wrB = packrow8(rowr +  88),
          wrC = packrow8(rowr +  96), wrD = packrow8(rowr + 104),
          wrE = packrow8(rowr + 112), wrF = packrow8(rowr + 120);
    u32x4 wz0 = packrow8(rowz +   0), wz1 = packrow8(rowz +   8),
          wz2 = packrow8(rowz +  16), wz3 = packrow8(rowz +  24),
          wz4 = packrow8(rowz +  32), wz5 = packrow8(rowz +  40),
          wz6 = packrow8(rowz +  48), wz7 = packrow8(rowz +  56),
          wz8 = packrow8(rowz +  64), wz9 = packrow8(rowz +  72),
          wzA = packrow8(rowz +  80), wzB = packrow8(rowz +  88),
          wzC = packrow8(rowz +  96), wzD = packrow8(rowz + 104),
          wzE = packrow8(rowz + 112), wzF = packrow8(rowz + 120);
    u32x4 wn0 = packrow8(rown +   0), wn1 = packrow8(rown +   8),
          wn2 = packrow8(rown +  16), wn3 = packrow8(rown +  24),
          wn4 = packrow8(rown +  32), wn5 = packrow8(rown +  40),
          wn6 = packrow8(rown +  48), wn7 = packrow8(rown +  56),
          wn8 = packrow8(rown +  64), wn9 = packrow8(rown +  72),
          wnA = packrow8(rown +  80), wnB = packrow8(rown +  88),
          wnC = packrow8(rown +  96), wnD = packrow8(rown + 104),
          wnE = packrow8(rown + 112), wnF = packrow8(rown + 120);
    asm volatile("" : "+v"(wr0), "+v"(wr1), "+v"(wr2), "+v"(wr3),
                      "+v"(wr4), "+v"(wr5), "+v"(wr6), "+v"(wr7),
                      "+v"(wr8), "+v"(wr9), "+v"(wrA), "+v"(wrB));
    asm volatile("" : "+v"(wrC), "+v"(wrD), "+v"(wrE), "+v"(wrF),
                      "+v"(wz0), "+v"(wz1), "+v"(wz2), "+v"(wz3),
                      "+v"(wz4), "+v"(wz5), "+v"(wz6), "+v"(wz7));
    asm volatile("" : "+v"(wz8), "+v"(wz9), "+v"(wzA), "+v"(wzB),
                      "+v"(wzC), "+v"(wzD), "+v"(wzE), "+v"(wzF),
                      "+v"(wn0), "+v"(wn1), "+v"(wn2), "+v"(wn3));
    asm volatile("" : "+v"(wn4), "+v"(wn5), "+v"(wn6), "+v"(wn7),
                      "+v"(wn8), "+v"(wn9), "+v"(wnA), "+v"(wnB),
                      "+v"(wnC), "+v"(wnD), "+v"(wnE), "+v"(wnF));

    const float L1 = 1.44269504f;                // log2(e)
    const float wihr_s = -L1 * Wih[j];
    const float wihz_s = -L1 * Wih[j + HH];
    const float wihn_s = 2.0f * L1 * Wih[j + 2 * HH];
    const float bihn_s = 2.0f * L1 * bih[j + 2 * HH];
    const float brz_r = bih[j]      + bhh[j];        // full bias (no pair split)
    const float brz_z = bih[j + HH] + bhh[j + HH];
    const float bhh_n = bhh[j + 2 * HH];

    float hp = h_prev[(d * BB + b) * HH + j];    // f32 carry
    hbuf[0][j] = (f16)hp;
    __syncthreads();

    // One GRU step: read FULL h (wave-uniform broadcast) from hbuf[SRC].
#define GSTEP(SRC, DST, TSS)                                                   \
    {                                                                          \
        const int tt = d ? (SS - 1 - (TSS)) : (TSS);                           \
        const float xv = xs[tt * CC + c];        /* uniform broadcast read */  \
        const u32x4* hb = reinterpret_cast<const u32x4*>(&hbuf[SRC][0]);       \
        const u32x4 h0 = hb[0],  h1 = hb[1],  h2 = hb[2],  h3 = hb[3],         \
                    h4 = hb[4],  h5 = hb[5],  h6 = hb[6],  h7 = hb[7],         \
                    h8 = hb[8],  h9 = hb[9],  hA = hb[10], hB = hb[11],        \
                    hC = hb[12], hD = hb[13], hE = hb[14], hF = hb[15];        \
        float r0 = dot4x2(wr0, h0, brz_r), r1 = dot4x2(wr1, h1, 0.f),          \
              r2 = dot4x2(wr2, h2, 0.f),   r3 = dot4x2(wr3, h3, 0.f);          \
        float z0 = dot4x2(wz0, h0, brz_z), z1 = dot4x2(wz1, h1, 0.f),          \
              z2 = dot4x2(wz2, h2, 0.f),   z3 = dot4x2(wz3, h3, 0.f);          \
        float n0 = dot4x2(wn0, h0, bhh_n), n1 = dot4x2(wn1, h1, 0.f),          \
              n2 = dot4x2(wn2, h2, 0.f),   n3 = dot4x2(wn3, h3, 0.f);          \
        r0 = dot4x2(wr4, h4, r0); r1 = dot4x2(wr5, h5, r1);                    \
        r2 = dot4x2(wr6, h6, r2); r3 = dot4x2(wr7, h7, r3);                    \
        z0 = dot4x2(wz4, h4, z0); z1 = dot4x2(wz5, h5, z1);                    \
        z2 = dot4x2(wz6, h6, z2); z3 = dot4x2(wz7, h7, z3);                    \
        n0 = dot4x2(wn4, h4, n0); n1 = dot4x2(wn5, h5, n1);                    \
        n2 = dot4x2(wn6, h6, n2); n3 = dot4x2(wn7, h7, n3);                    \
        r0 = dot4x2(wr8, h8, r0); r1 = dot4x2(wr9, h9, r1);                    \
        r2 = dot4x2(wrA, hA, r2); r3 = dot4x2(wrB, hB, r3);                    \
        z0 = dot4x2(wz8, h8, z0); z1 = dot4x2(wz9, h9, z1);                    \
        z2 = dot4x2(wzA, hA, z2); z3 = dot4x2(wzB, hB, z3);                    \
        n0 = dot4x2(wn8, h8, n0); n1 = dot4x2(wn9, h9, n1);                    \
        n2 = dot4x2(wnA, hA, n2); n3 = dot4x2(wnB, hB, n3);                    \
        r0 = dot4x2(wrC, hC, r0); r1 = dot4x2(wrD, hD, r1);                    \
        r2 = dot4x2(wrE, hE, r2); r3 = dot4x2(wrF, hF, r3);                    \
        z0 = dot4x2(wzC, hC, z0); z1 = dot4x2(wzD, hD, z1);                    \
        z2 = dot4x2(wzE, hE, z2); z3 = dot4x2(wzF, hF, z3);                    \
        n0 = dot4x2(wnC, hC, n0); n1 = dot4x2(wnD, hD, n1);                    \
        n2 = dot4x2(wnE, hE, n2); n3 = dot4x2(wnF, hF, n3);                    \
        const float sr = (r0 + r1) + (r2 + r3);                                \
        const float sz = (z0 + z1) + (z2 + z3);                                \
        const float sn = (n0 + n1) + (n2 + n3);                                \
        const float argr = fmaf(sr, -L1, xv * wihr_s);                         \
        const float argz = fmaf(sz, -L1, xv * wihz_s);                         \
        const float r = rcpn(1.0f + exp2n(argr));                              \
        const float z = rcpn(1.0f + exp2n(argz));                              \
        const float gin = fmaf(xv, wihn_s, bihn_s);                            \
        const float argn = fmaf(r, sn * (2.0f * L1), gin);                     \
        const float n = fmaf(-2.0f, rcpn(1.0f + exp2n(argn)), 1.0f);           \
        hp = fmaf(z, hp - n, n);                /* (1-z)*n + z*h  (f32) */     \
        hbuf[DST][j] = (f16)hp;                                                \
        __syncthreads();                                                       \
    }

    for (int c = 0; c < CC; ++c) {
        for (int ts = 0; ts < SS; ts += 2) {
            GSTEP(0, 1, ts)        // h: buf0 -> buf1
            GSTEP(1, 0, ts + 1)    // h: buf1 -> buf0
        }
        hsnap[(((size_t)d * CC + c) * BB + b) * HH + j] = hp;
    }
#undef GSTEP
}

// One block (= one wave of 64 threads) per (c,b): FC + ReLU + softmax over O=64.
__global__ __launch_bounds__(64) void fc_softmax_kernel(
    const float* __restrict__ hsnap,   // (2, C, B, H)
    const float* __restrict__ W_fc,    // (O, 2H)
    const float* __restrict__ b_fc,    // (O,)
    float* __restrict__ out)           // (B, C, O)
{
    const int cb = blockIdx.x;         // c * B + b
    const int c  = cb >> 5;
    const int b  = cb & 31;
    const int o  = threadIdx.x;        // 0..63

    __shared__ float feat[2 * HH];     // [hf, hb]
    #pragma unroll
    for (int i = 0; i < 4; ++i) {
        const int idx = i * 64 + o;            // 0..255
        const int dd  = idx >> 7;              // 0: hf, 1: hb
        const int jj  = idx & (HH - 1);
        feat[idx] = hsnap[(((size_t)dd * CC + c) * BB + b) * HH + jj];
    }
    __syncthreads();

    float acc = 0.f;
    const float4* wrow = reinterpret_cast<const float4*>(W_fc + o * 2 * HH);
    const float4* f4   = reinterpret_cast<const float4*>(feat);
    #pragma unroll
    for (int k = 0; k < 64; ++k) {
        const float4 wv = wrow[k];
        const float4 fv = f4[k];
        acc = fmaf(wv.x, fv.x, acc);
        acc = fmaf(wv.y, fv.y, acc);
        acc = fmaf(wv.z, fv.z, acc);
        acc = fmaf(wv.w, fv.w, acc);
    }
    float v = fmaxf(acc + b_fc[o], 0.0f);

    float m = v;
    #pragma unroll
    for (int off = 32; off; off >>= 1) m = fmaxf(m, __shfl_xor(m, off));
    const float e = __expf(v - m);
    float ssum = e;
    #pragma unroll
    for (int off = 32; off; off >>= 1) ssum += __shfl_xor(ssum, off);

    out[((size_t)b * CC + c) * OO + o] = e / ssum;
}

extern "C" void kernel_launch(void* const* d_in, const int* in_sizes, int n_in,
                              void* d_out, int out_size, void* d_ws, size_t ws_size,
                              hipStream_t stream) {
    const float* x      = (const float*)d_in[0];
    const float* h_prev = (const float*)d_in[1];
    const float* Wih_f  = (const float*)d_in[2];
    const float* Whh_f  = (const float*)d_in[3];
    const float* bih_f  = (const float*)d_in[4];
    const float* bhh_f  = (const float*)d_in[5];
    const float* Wih_b  = (const float*)d_in[6];
    const float* Whh_b  = (const float*)d_in[7];
    const float* bih_b  = (const float*)d_in[8];
    const float* bhh_b  = (const float*)d_in[9];
    const float* W_fc   = (const float*)d_in[10];
    const float* b_fc   = (const float*)d_in[11];
    float* out   = (float*)d_out;
    float* hsnap = (float*)d_ws;   // 2*C*B*H*4 = 4 MiB of scratch

    gru_chain_kernel<<<64, 128, 0, stream>>>(x, h_prev, Wih_f, Whh_f, bih_f, bhh_f,
                                             Wih_b, Whh_b, bih_b, bhh_b, hsnap);
    fc_softmax_kernel<<<CC * BB, 64, 0, stream>>>(hsnap, W_fc, b_fc, out);
}

// Round 19
// 10875.977 us; speedup vs baseline: 1.3830x; 1.3830x over previous
//
#include <hip/hip_runtime.h>
#include <hip/hip_bf16.h>

#define BB 32
#define SS 128
#define CC 128
#define HH 128
#define OO 64

typedef _Float16 f16;
typedef f16 h2 __attribute__((ext_vector_type(2)));
typedef f16 f16x8 __attribute__((ext_vector_type(8)));
typedef float f32x4 __attribute__((ext_vector_type(4)));
typedef unsigned u32x2 __attribute__((ext_vector_type(2)));
typedef unsigned u32x4 __attribute__((ext_vector_type(4)));

// Native single-instruction transcendentals (R17-proven: removed ~600 cyc of
// OCML expansion from the VALU-path kernel; R16's tail is 8x heavier).
__device__ __forceinline__ float exp2n(float x) {
    float r; asm("v_exp_f32 %0, %1" : "=v"(r) : "v"(x)); return r;
}
__device__ __forceinline__ float rcpn(float x) {
    float r; asm("v_rcp_f32 %0, %1" : "=v"(r) : "v"(x)); return r;
}

__device__ __forceinline__ unsigned pack2f(float a, float b) {
    h2 v; v[0] = (f16)a; v[1] = (f16)b;
    return __builtin_bit_cast(unsigned, v);
}
// 8 consecutive f32 -> f16x8. k-slot bijection shared by A-pack and B-layout
// (k = 8*(l>>4)+e within a K-tile) — HW-verified R14/R16 (absmax 1.22e-4).
__device__ __forceinline__ f16x8 packA8(const float* p) {
    u32x4 u;
    u.x = pack2f(p[0], p[1]); u.y = pack2f(p[2], p[3]);
    u.z = pack2f(p[4], p[5]); u.w = pack2f(p[6], p[7]);
    return __builtin_bit_cast(f16x8, u);
}
#define MFMA16(a, b, c) __builtin_amdgcn_mfma_f32_16x16x32_f16(a, b, c, 0, 0, 0)

#define L2E 1.44269504f   // log2(e)

// Gate math for 4 rows, native log2-domain trans. MFMA C/D layout
// (m89/R14-verified): col = lane&15 (batch), row = 4*(lane>>4)+e.
// wr_s = -L2E*wihr ; wz_s = -L2E*wihz ; wn_s2 = 2*L2E*wihn ; bn_s2 = 2*L2E*bihn.
__device__ __forceinline__ f32x4 gate4n(f32x4 cr, f32x4 cz, f32x4 cn,
                                        f32x4 wr_s, f32x4 wz_s, f32x4 wn_s2,
                                        f32x4 bn_s2, float xv, f32x4 hp) {
    f32x4 out;
    #pragma unroll
    for (int e = 0; e < 4; ++e) {
        const float argr = fmaf(cr[e], -L2E, xv * wr_s[e]);
        const float r    = rcpn(1.0f + exp2n(argr));
        const float argz = fmaf(cz[e], -L2E, xv * wz_s[e]);
        const float z    = rcpn(1.0f + exp2n(argz));
        const float gins = fmaf(xv, wn_s2[e], bn_s2[e]);
        const float argn = fmaf(r * (2.0f * L2E), cn[e], gins);
        const float n    = fmaf(-2.0f, rcpn(1.0f + exp2n(argn)), 1.0f);
        out[e] = fmaf(z, hp[e] - n, n);          // (1-z)*n + z*h
    }
    return out;
}

// ROUND-19 = R16 (MFMA-batched: one block = direction x 16 batches, per step
// a 384x16x128 GEMM, 24 MFMA/wave, resident A-frags at VGPR=124, xcol LDS
// staging) + NATIVE log2-domain gate tail. R16's 2550 cyc/step was ~1890 cyc
// VALU issue dominated by OCML __expf/div expansion (R17's discovery);
// native exp2/rcp cuts the tail ~4x. Biases stay linear in the MFMA seeds;
// log2 scaling folded into per-lane f32 constants.
__global__
__attribute__((amdgpu_flat_work_group_size(256, 256), amdgpu_waves_per_eu(1, 2)))
void gru_chain_kernel(
    const float* __restrict__ x,       // (B,S,C)
    const float* __restrict__ h_prev,  // (2,B,H)
    const float* __restrict__ Wih_f, const float* __restrict__ Whh_f,
    const float* __restrict__ bih_f, const float* __restrict__ bhh_f,
    const float* __restrict__ Wih_b, const float* __restrict__ Whh_b,
    const float* __restrict__ bih_b, const float* __restrict__ bhh_b,
    float* __restrict__ hsnap)         // (2, C, B, H)
{
    const int blk   = blockIdx.x;      // 0..3
    const int d     = blk >> 1;        // direction
    const int bbase = (blk & 1) << 4;  // batch half
    const int t  = threadIdx.x;        // 0..255
    const int w  = t >> 6;             // wave 0..3
    const int l  = t & 63;
    const int g  = l >> 4;             // k-group / D-row group
    const int la = l & 15;             // A-row within tile; B col (batch)
    const int bg = bbase + la;         // global batch for this lane

    const float* __restrict__ Wih = d ? Wih_b : Wih_f;
    const float* __restrict__ Whh = d ? Whh_b : Whh_f;
    const float* __restrict__ bih = d ? bih_b : bih_f;
    const float* __restrict__ bhh = d ? bhh_b : bhh_f;

    __shared__ __align__(16) f16 hl[2][16][136];  // [buf][batch][k], +8 pad
    __shared__ float xcol[SS * 16];               // column stage [ts][batch], 8KB

    // ---- A-fragments: 6 M-tiles (r0,r1,z0,z1,n0,n1) x 4 K-tiles ----
    const float* rR0 = Whh + ((size_t)(      32 * w + la)) * HH;
    const float* rR1 = rR0 + 16 * HH;
    const float* rZ0 = Whh + ((size_t)(128 + 32 * w + la)) * HH;
    const float* rZ1 = rZ0 + 16 * HH;
    const float* rN0 = Whh + ((size_t)(256 + 32 * w + la)) * HH;
    const float* rN1 = rN0 + 16 * HH;
    const int kb = 8 * g;
    f16x8 aR0k0 = packA8(rR0 + kb),      aR0k1 = packA8(rR0 + 32 + kb),
          aR0k2 = packA8(rR0 + 64 + kb), aR0k3 = packA8(rR0 + 96 + kb);
    f16x8 aR1k0 = packA8(rR1 + kb),      aR1k1 = packA8(rR1 + 32 + kb),
          aR1k2 = packA8(rR1 + 64 + kb), aR1k3 = packA8(rR1 + 96 + kb);
    f16x8 aZ0k0 = packA8(rZ0 + kb),      aZ0k1 = packA8(rZ0 + 32 + kb),
          aZ0k2 = packA8(rZ0 + 64 + kb), aZ0k3 = packA8(rZ0 + 96 + kb);
    f16x8 aZ1k0 = packA8(rZ1 + kb),      aZ1k1 = packA8(rZ1 + 32 + kb),
          aZ1k2 = packA8(rZ1 + 64 + kb), aZ1k3 = packA8(rZ1 + 96 + kb);
    f16x8 aN0k0 = packA8(rN0 + kb),      aN0k1 = packA8(rN0 + 32 + kb),
          aN0k2 = packA8(rN0 + 64 + kb), aN0k3 = packA8(rN0 + 96 + kb);
    f16x8 aN1k0 = packA8(rN1 + kb),      aN1k1 = packA8(rN1 + 32 + kb),
          aN1k2 = packA8(rN1 + 64 + kb), aN1k3 = packA8(rN1 + 96 + kb);
    asm volatile("" : "+v"(aR0k0), "+v"(aR0k1), "+v"(aR0k2), "+v"(aR0k3),
                      "+v"(aR1k0), "+v"(aR1k1), "+v"(aR1k2), "+v"(aR1k3),
                      "+v"(aZ0k0), "+v"(aZ0k1), "+v"(aZ0k2), "+v"(aZ0k3));
    asm volatile("" : "+v"(aZ1k0), "+v"(aZ1k1), "+v"(aZ1k2), "+v"(aZ1k3),
                      "+v"(aN0k0), "+v"(aN0k1), "+v"(aN0k2), "+v"(aN0k3),
                      "+v"(aN1k0), "+v"(aN1k1), "+v"(aN1k2), "+v"(aN1k3));

    // ---- Per-lane gate constants (D rows j0..j0+3 and j1..j1+3) ----
    const int j0 = 32 * w + 4 * g;
    const int j1 = j0 + 16;
    // log2-domain pre-scaled x-weights; biases stay linear in MFMA seeds.
    f32x4 wihr0 = -L2E * *(const f32x4*)(Wih + j0);
    f32x4 wihr1 = -L2E * *(const f32x4*)(Wih + j1);
    f32x4 wihz0 = -L2E * *(const f32x4*)(Wih + HH + j0);
    f32x4 wihz1 = -L2E * *(const f32x4*)(Wih + HH + j1);
    f32x4 wihn0 = (2.0f * L2E) * *(const f32x4*)(Wih + 2 * HH + j0);
    f32x4 wihn1 = (2.0f * L2E) * *(const f32x4*)(Wih + 2 * HH + j1);
    f32x4 bihn0 = (2.0f * L2E) * *(const f32x4*)(bih + 2 * HH + j0);
    f32x4 bihn1 = (2.0f * L2E) * *(const f32x4*)(bih + 2 * HH + j1);
    f32x4 seedr0 = *(const f32x4*)(bih + j0) + *(const f32x4*)(bhh + j0);
    f32x4 seedr1 = *(const f32x4*)(bih + j1) + *(const f32x4*)(bhh + j1);
    f32x4 seedz0 = *(const f32x4*)(bih + HH + j0) + *(const f32x4*)(bhh + HH + j0);
    f32x4 seedz1 = *(const f32x4*)(bih + HH + j1) + *(const f32x4*)(bhh + HH + j1);
    f32x4 seedn0 = *(const f32x4*)(bhh + 2 * HH + j0);
    f32x4 seedn1 = *(const f32x4*)(bhh + 2 * HH + j1);
    asm volatile("" : "+v"(wihr0), "+v"(wihr1), "+v"(wihz0), "+v"(wihz1),
                      "+v"(wihn0), "+v"(wihn1), "+v"(seedr0), "+v"(seedr1),
                      "+v"(seedz0), "+v"(seedz1), "+v"(seedn0), "+v"(seedn1),
                      "+v"(bihn0), "+v"(bihn1));

    // ---- h carry in f32 regs + f16 copy in LDS ----
    f32x4 hp0 = *(const f32x4*)(h_prev + ((size_t)d * BB + bg) * HH + j0);
    f32x4 hp1 = *(const f32x4*)(h_prev + ((size_t)d * BB + bg) * HH + j1);
    {
        u32x2 v0; v0.x = pack2f(hp0[0], hp0[1]); v0.y = pack2f(hp0[2], hp0[3]);
        u32x2 v1; v1.x = pack2f(hp1[0], hp1[1]); v1.y = pack2f(hp1[2], hp1[3]);
        *(u32x2*)&hl[0][la][j0] = v0;
        *(u32x2*)&hl[0][la][j1] = v1;
    }
    __syncthreads();

#define GSTEP(SRC, DST, TSS)                                                   \
    {                                                                          \
        const int tt = d ? (SS - 1 - (TSS)) : (TSS);                           \
        const float xv = xcol[tt * 16 + la];     /* LDS broadcast read */      \
        const f16* hbase = &hl[SRC][la][8 * g];                                \
        const f16x8 b0 = *(const f16x8*)(hbase);                               \
        const f16x8 b1 = *(const f16x8*)(hbase + 32);                          \
        const f16x8 b2 = *(const f16x8*)(hbase + 64);                          \
        const f16x8 b3 = *(const f16x8*)(hbase + 96);                          \
        f32x4 cr0 = seedr0, cz0 = seedz0, cn0 = seedn0;                        \
        f32x4 cr1 = seedr1, cz1 = seedz1, cn1 = seedn1;                        \
        cr0 = MFMA16(aR0k0, b0, cr0); cr0 = MFMA16(aR0k1, b1, cr0);            \
        cr0 = MFMA16(aR0k2, b2, cr0); cr0 = MFMA16(aR0k3, b3, cr0);            \
        cz0 = MFMA16(aZ0k0, b0, cz0); cz0 = MFMA16(aZ0k1, b1, cz0);            \
        cz0 = MFMA16(aZ0k2, b2, cz0); cz0 = MFMA16(aZ0k3, b3, cz0);            \
        cn0 = MFMA16(aN0k0, b0, cn0); cn0 = MFMA16(aN0k1, b1, cn0);            \
        cn0 = MFMA16(aN0k2, b2, cn0); cn0 = MFMA16(aN0k3, b3, cn0);            \
        cr1 = MFMA16(aR1k0, b0, cr1); cr1 = MFMA16(aR1k1, b1, cr1);            \
        cr1 = MFMA16(aR1k2, b2, cr1); cr1 = MFMA16(aR1k3, b3, cr1);            \
        cz1 = MFMA16(aZ1k0, b0, cz1); cz1 = MFMA16(aZ1k1, b1, cz1);            \
        cz1 = MFMA16(aZ1k2, b2, cz1); cz1 = MFMA16(aZ1k3, b3, cz1);            \
        cn1 = MFMA16(aN1k0, b0, cn1); cn1 = MFMA16(aN1k1, b1, cn1);            \
        cn1 = MFMA16(aN1k2, b2, cn1); cn1 = MFMA16(aN1k3, b3, cn1);            \
        hp0 = gate4n(cr0, cz0, cn0, wihr0, wihz0, wihn0, bihn0, xv, hp0);      \
        hp1 = gate4n(cr1, cz1, cn1, wihr1, wihz1, wihn1, bihn1, xv, hp1);      \
        u32x2 o0; o0.x = pack2f(hp0[0], hp0[1]); o0.y = pack2f(hp0[2], hp0[3]);\
        u32x2 o1; o1.x = pack2f(hp1[0], hp1[1]); o1.y = pack2f(hp1[2], hp1[3]);\
        *(u32x2*)&hl[DST][la][j0] = o0;                                        \
        *(u32x2*)&hl[DST][la][j1] = o1;                                        \
        __syncthreads();                                                       \
    }

    for (int cc = 0; cc < CC; ++cc) {
        // stage this column's x slice: 2048 floats, 8 per thread (L2-resident)
        #pragma unroll
        for (int i = 0; i < 8; ++i) {
            const int e  = t + i * 256;          // 0..2047
            const int ts = e >> 4;
            const int bb = e & 15;
            xcol[e] = x[((size_t)(bbase + bb) * SS + ts) * CC + cc];
        }
        __syncthreads();
        for (int ts = 0; ts < SS; ts += 2) {
            GSTEP(0, 1, ts)
            GSTEP(1, 0, ts + 1)
        }
        *(f32x4*)(hsnap + (((size_t)d * CC + cc) * BB + bg) * HH + j0) = hp0;
        *(f32x4*)(hsnap + (((size_t)d * CC + cc) * BB + bg) * HH + j1) = hp1;
    }
#undef GSTEP
}

// One block (= one wave of 64 threads) per (c,b): FC + ReLU + softmax over O=64.
__global__ __launch_bounds__(64) void fc_softmax_kernel(
    const float* __restrict__ hsnap,   // (2, C, B, H)
    const float* __restrict__ W_fc,    // (O, 2H)
    const float* __restrict__ b_fc,    // (O,)
    float* __restrict__ out)           // (B, C, O)
{
    const int cb = blockIdx.x;         // c * B + b
    const int c  = cb >> 5;
    const int b  = cb & 31;
    const int o  = threadIdx.x;        // 0..63

    __shared__ float feat[2 * HH];     // [hf, hb]
    #pragma unroll
    for (int i = 0; i < 4; ++i) {
        const int idx = i * 64 + o;            // 0..255
        const int dd  = idx >> 7;              // 0: hf, 1: hb
        const int jj  = idx & (HH - 1);
        feat[idx] = hsnap[(((size_t)dd * CC + c) * BB + b) * HH + jj];
    }
    __syncthreads();

    float acc = 0.f;
    const float4* wrow = reinterpret_cast<const float4*>(W_fc + o * 2 * HH);
    const float4* f4   = reinterpret_cast<const float4*>(feat);
    #pragma unroll
    for (int k = 0; k < 64; ++k) {
        const float4 wv = wrow[k];
        const float4 fv = f4[k];
        acc = fmaf(wv.x, fv.x, acc);
        acc = fmaf(wv.y, fv.y, acc);
        acc = fmaf(wv.z, fv.z, acc);
        acc = fmaf(wv.w, fv.w, acc);
    }
    float v = fmaxf(acc + b_fc[o], 0.0f);

    float m = v;
    #pragma unroll
    for (int off = 32; off; off >>= 1) m = fmaxf(m, __shfl_xor(m, off));
    const float e = __expf(v - m);
    float ssum = e;
    #pragma unroll
    for (int off = 32; off; off >>= 1) ssum += __shfl_xor(ssum, off);

    out[((size_t)b * CC + c) * OO + o] = e / ssum;
}

extern "C" void kernel_launch(void* const* d_in, const int* in_sizes, int n_in,
                              void* d_out, int out_size, void* d_ws, size_t ws_size,
                              hipStream_t stream) {
    const float* x      = (const float*)d_in[0];
    const float* h_prev = (const float*)d_in[1];
    const float* Wih_f  = (const float*)d_in[2];
    const float* Whh_f  = (const float*)d_in[3];
    const float* bih_f  = (const float*)d_in[4];
    const float* bhh_f  = (const float*)d_in[5];
    const float* Wih_b  = (const float*)d_in[6];
    const float* Whh_b  = (const float*)d_in[7];
    const float* bih_b  = (const float*)d_in[8];
    const float* bhh_b  = (const float*)d_in[9];
    const float* W_fc   = (const float*)d_in[10];
    const float* b_fc   = (const float*)d_in[11];
    float* out   = (float*)d_out;
    float* hsnap = (float*)d_ws;   // 2*C*B*H*4 = 4 MiB of scratch

    gru_chain_kernel<<<4, 256, 0, stream>>>(x, h_prev, Wih_f, Whh_f, bih_f, bhh_f,
                                            Wih_b, Whh_b, bih_b, bhh_b, hsnap);
    fc_softmax_kernel<<<CC * BB, 64, 0, stream>>>(hsnap, W_fc, b_fc, out);
}

// Round 20
// 6196.306 us; speedup vs baseline: 2.4274x; 1.7552x over previous
//
#include <hip/hip_runtime.h>
#include <hip/hip_bf16.h>

#define BB 32
#define SS 128
#define CC 128
#define HH 128
#define OO 64

typedef _Float16 f16;
typedef f16 h2 __attribute__((ext_vector_type(2)));
typedef unsigned u32x4 __attribute__((ext_vector_type(4)));   // 4 packed f16x2 pairs

// Forced-native transcendentals (R17-proven +13%; R19 confirmed on MFMA
// branch): v_exp_f32 (2^x) and v_rcp_f32 via asm cannot be OCML-expanded.
// |args| < 64 here: no range issues.
__device__ __forceinline__ float exp2n(float x) {
    float r; asm("v_exp_f32 %0, %1" : "=v"(r) : "v"(x)); return r;
}
__device__ __forceinline__ float rcpn(float x) {
    float r; asm("v_rcp_f32 %0, %1" : "=v"(r) : "v"(x)); return r;
}

// Pair butterfly add on the VALU pipe (DPP quad_perm xor1).
__device__ __forceinline__ float dpp_add_x1(float v) {
    int m = __builtin_amdgcn_update_dpp(0, __builtin_bit_cast(int, v),
                                        0xB1, 0xF, 0xF, true);
    return v + __builtin_bit_cast(float, m);
}

__device__ __forceinline__ h2 as_h2(unsigned u) { return __builtin_bit_cast(h2, u); }

__device__ __forceinline__ unsigned pack2f(float a, float b) {
    h2 v; v[0] = (f16)a; v[1] = (f16)b;
    return __builtin_bit_cast(unsigned, v);
}
__device__ __forceinline__ u32x4 packrow8(const float* p) {
    u32x4 r;
    r.x = pack2f(p[0], p[1]);
    r.y = pack2f(p[2], p[3]);
    r.z = pack2f(p[4], p[5]);
    r.w = pack2f(p[6], p[7]);
    return r;
}

// 8-elem f16 dot, f32 accumulate; all operands pre-packed f16x2 pairs.
__device__ __forceinline__ float dot4x2(u32x4 w, u32x4 h, float acc) {
    acc = __builtin_amdgcn_fdot2(as_h2(w.x), as_h2(h.x), acc, false);
    acc = __builtin_amdgcn_fdot2(as_h2(w.y), as_h2(h.y), acc, false);
    acc = __builtin_amdgcn_fdot2(as_h2(w.z), as_h2(h.z), acc, false);
    acc = __builtin_amdgcn_fdot2(as_h2(w.w), as_h2(h.w), acc, false);
    return acc;
}

// SESSION-BEST STRUCTURE (R17, 6213us): one workgroup per (direction,batch);
// 256 thr = 4 waves = 1/SIMD. Thread (j = t>>1, half = t&1) computes gate
// rows j / j+128 / j+256 over a 64-elem half of the 128-wide dot; 24 named
// u32x4 = 96 pinned weight VGPRs, RESIDENT at VGPR_Count=132 (the allocator
// grants ~132 max in every config tried; 512-thr blocks get 88-108 -> remat).
// LDS inflated >80KB -> 1 block/CU -> relaxed allocator budget. One dpp
// reduce stage; native exp2/rcp gates in the log2 domain:
//   sigmoid(a) = rcp(1 + exp2(-L*a)),  tanh(y) = 1 - 2*rcp(1 + exp2(2L*y))
// with L=log2(e) pre-folded into per-lane f32 constants. 1 barrier/step.
__global__
__attribute__((amdgpu_flat_work_group_size(256, 256), amdgpu_waves_per_eu(1, 2)))
void gru_chain_kernel(
    const float* __restrict__ x,       // (B,S,C)
    const float* __restrict__ h_prev,  // (2,B,H)
    const float* __restrict__ Wih_f, const float* __restrict__ Whh_f,
    const float* __restrict__ bih_f, const float* __restrict__ bhh_f,
    const float* __restrict__ Wih_b, const float* __restrict__ Whh_b,
    const float* __restrict__ bih_b, const float* __restrict__ bhh_b,
    float* __restrict__ hsnap)         // (2, C, B, H) column-end snapshots
{
    const int wg   = blockIdx.x;
    const int d    = wg >> 5;      // 0 = forward, 1 = backward
    const int b    = wg & 31;
    const int t    = threadIdx.x;  // 0..255
    const int j    = t >> 1;       // hidden index 0..127
    const int half = t & 1;        // which 64-elem half of the dot

    const float* __restrict__ Wih = d ? Wih_b : Wih_f;
    const float* __restrict__ Whh = d ? Whh_b : Whh_f;
    const float* __restrict__ bih = d ? bih_b : bih_f;
    const float* __restrict__ bhh = d ? bhh_b : bhh_f;

    // xs padded: total LDS > 80KB -> 1 block/CU -> relaxed VGPR budget.
    __shared__ float xs[SS * CC + 4608];
    __shared__ __align__(16) f16 hbuf[2][160];   // half at f16-offset half*72

    // stage x[b] (16384 contiguous floats) into LDS, coalesced float4
    {
        const float4* xb4 = reinterpret_cast<const float4*>(x + (size_t)b * SS * CC);
        float4* xs4 = reinterpret_cast<float4*>(xs);
        #pragma unroll
        for (int i = 0; i < 16; ++i) xs4[t + i * 256] = xb4[t + i * 256];
    }

    // 24 NAMED u32x4 (96 VGPRs) of packed f16 pairs: rows j, j+128, j+256,
    // this thread's 64-element half.
    const float* rowr = Whh + (j          ) * HH + half * 64;
    const float* rowz = Whh + (j +     HH ) * HH + half * 64;
    const float* rown = Whh + (j + 2 * HH ) * HH + half * 64;
    u32x4 wr0 = packrow8(rowr +  0), wr1 = packrow8(rowr +  8),
          wr2 = packrow8(rowr + 16), wr3 = packrow8(rowr + 24),
          wr4 = packrow8(rowr + 32), wr5 = packrow8(rowr + 40),
          wr6 = packrow8(rowr + 48), wr7 = packrow8(rowr + 56);
    u32x4 wz0 = packrow8(rowz +  0), wz1 = packrow8(rowz +  8),
          wz2 = packrow8(rowz + 16), wz3 = packrow8(rowz + 24),
          wz4 = packrow8(rowz + 32), wz5 = packrow8(rowz + 40),
          wz6 = packrow8(rowz + 48), wz7 = packrow8(rowz + 56);
    u32x4 wn0 = packrow8(rown +  0), wn1 = packrow8(rown +  8),
          wn2 = packrow8(rown + 16), wn3 = packrow8(rown + 24),
          wn4 = packrow8(rown + 32), wn5 = packrow8(rown + 40),
          wn6 = packrow8(rown + 48), wn7 = packrow8(rown + 56);
    asm volatile("" : "+v"(wr0), "+v"(wr1), "+v"(wr2), "+v"(wr3),
                      "+v"(wr4), "+v"(wr5), "+v"(wr6), "+v"(wr7),
                      "+v"(wz0), "+v"(wz1), "+v"(wz2), "+v"(wz3));
    asm volatile("" : "+v"(wz4), "+v"(wz5), "+v"(wz6), "+v"(wz7),
                      "+v"(wn0), "+v"(wn1), "+v"(wn2), "+v"(wn3),
                      "+v"(wn4), "+v"(wn5), "+v"(wn6), "+v"(wn7));

    const float L1 = 1.44269504f;                // log2(e)
    // log2-domain pre-scaled per-lane constants (f32, exact muls)
    const float wihr_s = -L1 * Wih[j];
    const float wihz_s = -L1 * Wih[j + HH];
    const float wihn_s = 2.0f * L1 * Wih[j + 2 * HH];
    const float bihn_s = 2.0f * L1 * bih[j + 2 * HH];
    const float brz_r2 = 0.5f * (bih[j]      + bhh[j]);      // pair-seeded bias
    const float brz_z2 = 0.5f * (bih[j + HH] + bhh[j + HH]);
    const float bhh_n2 = 0.5f * bhh[j + 2 * HH];

    float hp = h_prev[(d * BB + b) * HH + j];    // f32 carry (both lanes)
    const int hwr = ((j >> 6) * 72) + (j & 63);  // skewed write slot (f16 idx)
    if (half == 0) hbuf[0][hwr] = (f16)hp;
    __syncthreads();

    // One GRU step: read h (f16 pairs) from hbuf[SRC], write new h to hbuf[DST].
#define GSTEP(SRC, DST, TSS)                                                   \
    {                                                                          \
        const int tt = d ? (SS - 1 - (TSS)) : (TSS);                           \
        const float xv = xs[tt * CC + c];        /* uniform broadcast read */  \
        const u32x4* hb =                                                      \
            reinterpret_cast<const u32x4*>(&hbuf[SRC][half * 72]);             \
        const u32x4 h0 = hb[0], h1 = hb[1], h2 = hb[2], h3 = hb[3],            \
                    h4 = hb[4], h5 = hb[5], h6 = hb[6], h7 = hb[7];            \
        float r0 = dot4x2(wr0, h0, brz_r2), r1 = dot4x2(wr1, h1, 0.f),         \
              r2 = dot4x2(wr2, h2, 0.f),    r3 = dot4x2(wr3, h3, 0.f);         \
        float z0 = dot4x2(wz0, h0, brz_z2), z1 = dot4x2(wz1, h1, 0.f),         \
              z2 = dot4x2(wz2, h2, 0.f),    z3 = dot4x2(wz3, h3, 0.f);         \
        float n0 = dot4x2(wn0, h0, bhh_n2), n1 = dot4x2(wn1, h1, 0.f),         \
              n2 = dot4x2(wn2, h2, 0.f),    n3 = dot4x2(wn3, h3, 0.f);         \
        r0 = dot4x2(wr4, h4, r0); r1 = dot4x2(wr5, h5, r1);                    \
        r2 = dot4x2(wr6, h6, r2); r3 = dot4x2(wr7, h7, r3);                    \
        z0 = dot4x2(wz4, h4, z0); z1 = dot4x2(wz5, h5, z1);                    \
        z2 = dot4x2(wz6, h6, z2); z3 = dot4x2(wz7, h7, z3);                    \
        n0 = dot4x2(wn4, h4, n0); n1 = dot4x2(wn5, h5, n1);                    \
        n2 = dot4x2(wn6, h6, n2); n3 = dot4x2(wn7, h7, n3);                    \
        float sr = (r0 + r1) + (r2 + r3);                                      \
        float sz = (z0 + z1) + (z2 + z3);                                      \
        float sn = (n0 + n1) + (n2 + n3);                                      \
        sr = dpp_add_x1(sr);                    /* one reduce stage */         \
        sz = dpp_add_x1(sz);                                                   \
        sn = dpp_add_x1(sn);                                                   \
        /* gates in log2 domain, single-trans ops */                           \
        const float argr = fmaf(sr, -L1, xv * wihr_s);                         \
        const float argz = fmaf(sz, -L1, xv * wihz_s);                         \
        const float r = rcpn(1.0f + exp2n(argr));                              \
        const float z = rcpn(1.0f + exp2n(argz));                              \
        const float gin = fmaf(xv, wihn_s, bihn_s);                            \
        const float argn = fmaf(r, sn * (2.0f * L1), gin);                     \
        const float n = fmaf(-2.0f, rcpn(1.0f + exp2n(argn)), 1.0f);           \
        hp = fmaf(z, hp - n, n);                /* (1-z)*n + z*h  (f32) */     \
        if (half == 0) hbuf[DST][hwr] = (f16)hp;                               \
        __syncthreads();                                                       \
    }

    for (int c = 0; c < CC; ++c) {
        for (int ts = 0; ts < SS; ts += 2) {
            GSTEP(0, 1, ts)        // h: buf0 -> buf1
            GSTEP(1, 0, ts + 1)    // h: buf1 -> buf0
        }
        if (half == 0) {
            hsnap[(((size_t)d * CC + c) * BB + b) * HH + j] = hp;
        }
    }
#undef GSTEP
}

// One block (= one wave of 64 threads) per (c,b): FC + ReLU + softmax over O=64.
__global__ __launch_bounds__(64) void fc_softmax_kernel(
    const float* __restrict__ hsnap,   // (2, C, B, H)
    const float* __restrict__ W_fc,    // (O, 2H)
    const float* __restrict__ b_fc,    // (O,)
    float* __restrict__ out)           // (B, C, O)
{
    const int cb = blockIdx.x;         // c * B + b
    const int c  = cb >> 5;
    const int b  = cb & 31;
    const int o  = threadIdx.x;        // 0..63

    __shared__ float feat[2 * HH];     // [hf, hb]
    #pragma unroll
    for (int i = 0; i < 4; ++i) {
        const int idx = i * 64 + o;            // 0..255
        const int dd  = idx >> 7;              // 0: hf, 1: hb
        const int jj  = idx & (HH - 1);
        feat[idx] = hsnap[(((size_t)dd * CC + c) * BB + b) * HH + jj];
    }
    __syncthreads();

    float acc = 0.f;
    const float4* wrow = reinterpret_cast<const float4*>(W_fc + o * 2 * HH);
    const float4* f4   = reinterpret_cast<const float4*>(feat);
    #pragma unroll
    for (int k = 0; k < 64; ++k) {
        const float4 wv = wrow[k];
        const float4 fv = f4[k];
        acc = fmaf(wv.x, fv.x, acc);
        acc = fmaf(wv.y, fv.y, acc);
        acc = fmaf(wv.z, fv.z, acc);
        acc = fmaf(wv.w, fv.w, acc);
    }
    float v = fmaxf(acc + b_fc[o], 0.0f);

    float m = v;
    #pragma unroll
    for (int off = 32; off; off >>= 1) m = fmaxf(m, __shfl_xor(m, off));
    const float e = __expf(v - m);
    float ssum = e;
    #pragma unroll
    for (int off = 32; off; off >>= 1) ssum += __shfl_xor(ssum, off);

    out[((size_t)b * CC + c) * OO + o] = e / ssum;
}

extern "C" void kernel_launch(void* const* d_in, const int* in_sizes, int n_in,
                              void* d_out, int out_size, void* d_ws, size_t ws_size,
                              hipStream_t stream) {
    const float* x      = (const float*)d_in[0];
    const float* h_prev = (const float*)d_in[1];
    const float* Wih_f  = (const float*)d_in[2];
    const float* Whh_f  = (const float*)d_in[3];
    const float* bih_f  = (const float*)d_in[4];
    const float* bhh_f  = (const float*)d_in[5];
    const float* Wih_b  = (const float*)d_in[6];
    const float* Whh_b  = (const float*)d_in[7];
    const float* bih_b  = (const float*)d_in[8];
    const float* bhh_b  = (const float*)d_in[9];
    const float* W_fc   = (const float*)d_in[10];
    const float* b_fc   = (const float*)d_in[11];
    float* out   = (float*)d_out;
    float* hsnap = (float*)d_ws;   // 2*C*B*H*4 = 4 MiB of scratch

    gru_chain_kernel<<<64, 256, 0, stream>>>(x, h_prev, Wih_f, Whh_f, bih_f, bhh_f,
                                             Wih_b, Whh_b, bih_b, bhh_b, hsnap);
    fc_softmax_kernel<<<CC * BB, 64, 0, stream>>>(hsnap, W_fc, b_fc, out);
}